// Round 5
// baseline (1400.514 us; speedup 1.0000x reference)
//
#include <hip/hip_runtime.h>

#define ALPHA_C 0.05f
#define BETA_C  0.95f
#define GAMMA_C 0.95f

constexpr int B = 16, T = 24, N = 512, F = 2, H = 64, E = 16;
constexpr int DA = 8;
constexpr int CC = F + H;    // 66
constexpr int TGN_OC = 32;
constexpr int NPART = 8;     // K-eighth partials (both hyper and rnn paths)

__device__ __forceinline__ float fast_rcp(float x) { return __builtin_amdgcn_rcpf(x); }
__device__ __forceinline__ float fast_tanh(float x) {
    return 1.0f - 2.0f * fast_rcp(__expf(2.0f * x) + 1.0f);
}
__device__ __forceinline__ float fast_sigmoid(float x) {
    return fast_rcp(1.0f + __expf(-x));
}

// K1 = GAMMA*A (one-time)
__global__ void scaleA_kernel(const float* __restrict__ A, float* __restrict__ K1)
{
    int i = blockIdx.x * 256 + threadIdx.x;
    K1[i] = GAMMA_C * A[i];
}

// K2 = GAMMA*ALPHA*A + GAMMA^2 * A@A (one-time). Grid (32,32), 256 thr.
__global__ __launch_bounds__(256) void k2_kernel(const float* __restrict__ A,
                                                 float* __restrict__ K2)
{
    __shared__ float rows[16][258];
    __shared__ float cols[256][17];
    const int tid = threadIdx.x;
    const int r0 = blockIdx.y * 16, c0 = blockIdx.x * 16;
    const int rr = tid >> 4, cc = tid & 15;
    float acc = 0.f;
    for (int k0 = 0; k0 < N; k0 += 256) {
#pragma unroll
        for (int it = 0; it < 4; ++it) {
            int l = it * 256 + tid;
            int row = l >> 6, k4 = (l & 63) << 2;
            *(float4*)&rows[row][k4] = *(const float4*)(A + (size_t)(r0 + row) * N + k0 + k4);
        }
#pragma unroll
        for (int it = 0; it < 4; ++it) {
            int l = it * 256 + tid;
            int k = l >> 2, c4 = (l & 3) << 2;
            *(float4*)&cols[k][c4] = *(const float4*)(A + (size_t)(k0 + k) * N + c0 + c4);
        }
        __syncthreads();
#pragma unroll 8
        for (int k = 0; k < 256; ++k) acc += rows[rr][k] * cols[k][cc];
        __syncthreads();
    }
    size_t i = (size_t)(r0 + rr) * N + c0 + cc;
    K2[i] = GAMMA_C * ALPHA_C * A[i] + GAMMA_C * GAMMA_C * acc;
}

// ---------------------------------------------------------------------------
// bmm4 v5 (rnn path): grid (8, 8, B) = 1024 blocks, 256 thr (4 waves).
// Block = 64w x 66c output tile over one K-eighth (64 rows). Per-thread 4x4.
// Inner j: 2x ds_read_b128 (+ masked b32 g) for 16 FMA.
// LDS 33.4 KB -> 4 blocks/CU = 16 waves/CU.
// out_part[vq][b,w,c] = (vq==0 ? ALPHA*x : 0) + sum_{v in eighth} M[v,w]*in[b,v,c]
// ---------------------------------------------------------------------------
template<bool INSUM>
__global__ __launch_bounds__(256) void bmm4_kernel(
    float* __restrict__ out, const float* __restrict__ x, const float* __restrict__ in,
    const float* __restrict__ M)
{
    __shared__ float sh_m[64][64];
    __shared__ float sh_h[64][68];
    constexpr int Crow = CC;          // 66
    const size_t pstr = (size_t)B * N * Crow;
    const int tid = threadIdx.x;
    const int b = blockIdx.z, w0 = blockIdx.x * 64, vq = blockIdx.y;
    const int cg = tid & 15;          // 4 cols
    const int wg = tid >> 4;          // 0..15: 4 w rows
    const int v0 = vq * 64;

    const float* Mb = M + (size_t)b * N * N + (size_t)v0 * N + w0;
    const float* inb = in + (size_t)b * N * Crow + (size_t)v0 * Crow;

#pragma unroll
    for (int it = 0; it < 4; ++it) {
        int l = it * 256 + tid;
        int row = l >> 4, c4 = (l & 15) << 2;
        *(float4*)&sh_m[row][c4] = *(const float4*)(Mb + (size_t)row * N + c4);
    }
    for (int l = tid; l < 64 * 33; l += 256) {
        int row = l / 33, k = (l - row * 33) * 2;
        const float* src = inb + (size_t)row * Crow + k;
        float2 v = *(const float2*)src;
        if (INSUM) {
#pragma unroll
            for (int j = 1; j < NPART; ++j) {
                float2 w = *(const float2*)(src + (size_t)j * pstr);
                v.x += w.x; v.y += w.y;
            }
        }
        *(float2*)&sh_h[row][k] = v;
    }
    __syncthreads();

    float acc[4][4] = {{0,0,0,0},{0,0,0,0},{0,0,0,0},{0,0,0,0}};
    float ag[4] = {0.f, 0.f, 0.f, 0.f};
#pragma unroll 8
    for (int j = 0; j < 64; ++j) {
        float4 mv = *(const float4*)&sh_m[j][wg << 2];
        float4 hv = *(const float4*)&sh_h[j][cg << 2];
        acc[0][0] += mv.x * hv.x; acc[0][1] += mv.x * hv.y;
        acc[0][2] += mv.x * hv.z; acc[0][3] += mv.x * hv.w;
        acc[1][0] += mv.y * hv.x; acc[1][1] += mv.y * hv.y;
        acc[1][2] += mv.y * hv.z; acc[1][3] += mv.y * hv.w;
        acc[2][0] += mv.z * hv.x; acc[2][1] += mv.z * hv.y;
        acc[2][2] += mv.z * hv.z; acc[2][3] += mv.z * hv.w;
        acc[3][0] += mv.w * hv.x; acc[3][1] += mv.w * hv.y;
        acc[3][2] += mv.w * hv.z; acc[3][3] += mv.w * hv.w;
        if (cg < 2) {
            float gv = sh_h[j][64 + cg];
            ag[0] += mv.x * gv; ag[1] += mv.y * gv;
            ag[2] += mv.z * gv; ag[3] += mv.w * gv;
        }
    }

    float* outp = out + (size_t)vq * pstr + (size_t)b * N * Crow;
    const float* xb = x + (size_t)b * N * Crow;
#pragma unroll
    for (int r = 0; r < 4; ++r) {
        const int w = w0 + (wg << 2) + r;
        const size_t base = (size_t)w * Crow + (cg << 2);
        float o0 = acc[r][0], o1 = acc[r][1], o2 = acc[r][2], o3 = acc[r][3];
        if (vq == 0) {
            o0 += ALPHA_C * xb[base];     o1 += ALPHA_C * xb[base + 1];
            o2 += ALPHA_C * xb[base + 2]; o3 += ALPHA_C * xb[base + 3];
        }
        float2 lo = {o0, o1}, hi = {o2, o3};
        *(float2*)(outp + base) = lo;
        *(float2*)(outp + base + 2) = hi;
        if (cg < 2) {
            size_t gb = (size_t)w * Crow + 64 + cg;
            float v = ag[r];
            if (vq == 0) v += ALPHA_C * xb[gb];
            outp[gb] = v;
        }
    }
}

// ---------------------------------------------------------------------------
// hyper4: fused K1+K2, grid (8, 8, B) = 1024 blocks, 256 thr, per-thread 4x4
// for BOTH outputs over one K-eighth. Per j: 3x ds_read_b128 for 32 FMA.
// LDS 48 KB -> 3 blocks/CU.
// ---------------------------------------------------------------------------
__global__ __launch_bounds__(256) void hyper4_kernel(
    float* __restrict__ P1, float* __restrict__ P2, const float* __restrict__ hidden,
    const float* __restrict__ K1, const float* __restrict__ K2)
{
    __shared__ float sh_m1[64][64];
    __shared__ float sh_m2[64][64];
    __shared__ float sh_h[64][64];
    const size_t pstr = (size_t)B * N * H;
    const int tid = threadIdx.x;
    const int b = blockIdx.z, w0 = blockIdx.x * 64, vq = blockIdx.y;
    const int cg = tid & 15;
    const int wg = tid >> 4;          // 0..15
    const int v0 = vq * 64;
    const float* inb = hidden + (size_t)b * N * H;

#pragma unroll
    for (int it = 0; it < 4; ++it) {
        int l = it * 256 + tid;
        int row = l >> 4, c4 = (l & 15) << 2;
        *(float4*)&sh_m1[row][c4] = *(const float4*)(K1 + (size_t)(v0 + row) * N + w0 + c4);
        *(float4*)&sh_m2[row][c4] = *(const float4*)(K2 + (size_t)(v0 + row) * N + w0 + c4);
        *(float4*)&sh_h[row][c4]  = *(const float4*)(inb + (size_t)(v0 + row) * H + c4);
    }
    __syncthreads();

    float a1[4][4] = {{0,0,0,0},{0,0,0,0},{0,0,0,0},{0,0,0,0}};
    float a2[4][4] = {{0,0,0,0},{0,0,0,0},{0,0,0,0},{0,0,0,0}};
#pragma unroll 4
    for (int j = 0; j < 64; ++j) {
        float4 m1 = *(const float4*)&sh_m1[j][wg << 2];
        float4 m2 = *(const float4*)&sh_m2[j][wg << 2];
        float4 hv = *(const float4*)&sh_h[j][cg << 2];
        a1[0][0] += m1.x * hv.x; a1[0][1] += m1.x * hv.y;
        a1[0][2] += m1.x * hv.z; a1[0][3] += m1.x * hv.w;
        a1[1][0] += m1.y * hv.x; a1[1][1] += m1.y * hv.y;
        a1[1][2] += m1.y * hv.z; a1[1][3] += m1.y * hv.w;
        a1[2][0] += m1.z * hv.x; a1[2][1] += m1.z * hv.y;
        a1[2][2] += m1.z * hv.z; a1[2][3] += m1.z * hv.w;
        a1[3][0] += m1.w * hv.x; a1[3][1] += m1.w * hv.y;
        a1[3][2] += m1.w * hv.z; a1[3][3] += m1.w * hv.w;
        a2[0][0] += m2.x * hv.x; a2[0][1] += m2.x * hv.y;
        a2[0][2] += m2.x * hv.z; a2[0][3] += m2.x * hv.w;
        a2[1][0] += m2.y * hv.x; a2[1][1] += m2.y * hv.y;
        a2[1][2] += m2.y * hv.z; a2[1][3] += m2.y * hv.w;
        a2[2][0] += m2.z * hv.x; a2[2][1] += m2.z * hv.y;
        a2[2][2] += m2.z * hv.z; a2[2][3] += m2.z * hv.w;
        a2[3][0] += m2.w * hv.x; a2[3][1] += m2.w * hv.y;
        a2[3][2] += m2.w * hv.z; a2[3][3] += m2.w * hv.w;
    }
    float* o1 = P1 + (size_t)vq * pstr + (size_t)b * N * H;
    float* o2 = P2 + (size_t)vq * pstr + (size_t)b * N * H;
#pragma unroll
    for (int r = 0; r < 4; ++r) {
        const int w = w0 + (wg << 2) + r;
        const size_t base = (size_t)w * H + (cg << 2);
        float4 v1 = {a1[r][0], a1[r][1], a1[r][2], a1[r][3]};
        float4 v2 = {a2[r][0], a2[r][1], a2[r][2], a2[r][3]};
        if (vq == 0) {
            float4 xv = *(const float4*)(inb + base);
            v1.x += ALPHA_C * xv.x; v1.y += ALPHA_C * xv.y;
            v1.z += ALPHA_C * xv.z; v1.w += ALPHA_C * xv.w;
            v2.x += ALPHA_C * xv.x; v2.y += ALPHA_C * xv.y;
            v2.z += ALPHA_C * xv.z; v2.w += ALPHA_C * xv.w;
        }
        *(float4*)(o1 + base) = v1;
        *(float4*)(o2 + base) = v2;
    }
}

// ---------------------------------------------------------------------------
// gsgt5: 16-row slabs (grid 512), 256 thr. Sums 8 hyper partials.
// ---------------------------------------------------------------------------
__global__ __launch_bounds__(256) void gsgt5_kernel(
    const float* __restrict__ hidden, const float* __restrict__ P1, const float* __restrict__ P2,
    const float* __restrict__ Wa1, const float* __restrict__ ba1,
    const float* __restrict__ Wa2, const float* __restrict__ ba2,
    const float* __restrict__ graph, long gstride,
    const float* __restrict__ Wsrc, const float* __restrict__ bsrc,
    const float* __restrict__ Wtgt, const float* __restrict__ btgt,
    float* __restrict__ nv_s, float* __restrict__ nv_t)
{
    constexpr size_t psH = (size_t)B * N * H;
    __shared__ float sh[16][196];
    __shared__ float W1t[16][196];
    __shared__ float W2t[16][196];
    const int tid = threadIdx.x;
    const int e = tid & 15;
    const int row = tid >> 4;
    const size_t nn0 = (size_t)blockIdx.x * 16;
    {
        int f4 = ((int)(nn0) + row) * 16 + e;
        float4 v = ((const float4*)hidden)[f4];
        *(float4*)&sh[row][e << 2] = v;
        float4 a = ((const float4*)P1)[f4];
#pragma unroll
        for (int j = 1; j < NPART; ++j) {
            float4 w = ((const float4*)(P1 + (size_t)j * psH))[f4];
            a.x += w.x; a.y += w.y; a.z += w.z; a.w += w.w;
        }
        *(float4*)&sh[row][64 + (e << 2)] = a;
        float4 c = ((const float4*)P2)[f4];
#pragma unroll
        for (int j = 1; j < NPART; ++j) {
            float4 w = ((const float4*)(P2 + (size_t)j * psH))[f4];
            c.x += w.x; c.y += w.y; c.z += w.z; c.w += w.w;
        }
        *(float4*)&sh[row][128 + (e << 2)] = c;
    }
    for (int l = tid; l < 768; l += 256) {
        int sk = l >> 2, q = l & 3;
        float4 w1 = ((const float4*)Wa1)[l];
        float4 w2 = ((const float4*)Wa2)[l];
        W1t[4 * q + 0][sk] = w1.x; W1t[4 * q + 1][sk] = w1.y;
        W1t[4 * q + 2][sk] = w1.z; W1t[4 * q + 3][sk] = w1.w;
        W2t[4 * q + 0][sk] = w2.x; W2t[4 * q + 1][sk] = w2.y;
        W2t[4 * q + 2][sk] = w2.z; W2t[4 * q + 3][sk] = w2.w;
    }
    __syncthreads();
    float gs = ba1[e], gt = ba2[e];
#pragma unroll 8
    for (int sk = 0; sk < 192; sk += 4) {
        float4 xv = *(const float4*)&sh[row][sk];
        float4 w1 = *(const float4*)&W1t[e][sk];
        float4 w2 = *(const float4*)&W2t[e][sk];
        gs += xv.x * w1.x + xv.y * w1.y + xv.z * w1.z + xv.w * w1.w;
        gt += xv.x * w2.x + xv.y * w2.y + xv.z * w2.z + xv.w * w2.w;
    }
    size_t nn = nn0 + row;
    int b = (int)(nn >> 9), n = (int)(nn & (N - 1));
    const float* g = graph + (size_t)b * gstride + (size_t)n * F;
    float g0 = g[0], g1 = g[1];
    float es = g0 * Wsrc[e] + g1 * Wsrc[E + e] + bsrc[e];
    float et = g0 * Wtgt[e] + g1 * Wtgt[E + e] + btgt[e];
    nv_s[nn * E + e] = fast_tanh(2.0f * es * gs);
    nv_t[nn * E + e] = fast_tanh(2.0f * et * gt);
}

// ---------------------------------------------------------------------------
// adp: 4 rows/block, grid (128,16), 512 thr.
// ---------------------------------------------------------------------------
__global__ __launch_bounds__(512) void adp3_kernel(
    const float* __restrict__ nv_s, const float* __restrict__ nv_t,
    const float* __restrict__ A,
    const float* __restrict__ hidden, const float* __restrict__ graph, long gstride,
    float* __restrict__ Mcomb, float* __restrict__ comb)
{
    __shared__ float red[8][4];
    __shared__ float tot[4];
    const int m = threadIdx.x;
    const int n0 = blockIdx.x * 4;
    const int b = blockIdx.y;
    const float4* sm = (const float4*)(nv_s + ((size_t)b * N + m) * E);
    const float4* tm = (const float4*)(nv_t + ((size_t)b * N + m) * E);
    const float4* sn = (const float4*)(nv_s + ((size_t)b * N + n0) * E);
    const float4* tn = (const float4*)(nv_t + ((size_t)b * N + n0) * E);
    float a1[4] = {0.f,0.f,0.f,0.f}, a2[4] = {0.f,0.f,0.f,0.f};
#pragma unroll
    for (int dd = 0; dd < 4; ++dd) {
        float4 smv = sm[dd], tmv = tm[dd];
#pragma unroll
        for (int r = 0; r < 4; ++r) {
            float4 snv = sn[r * 4 + dd], tnv = tn[r * 4 + dd];
            a1[r] += snv.x * tmv.x + snv.y * tmv.y + snv.z * tmv.z + snv.w * tmv.w;
            a2[r] += tnv.x * smv.x + tnv.y * smv.y + tnv.z * smv.z + tnv.w * smv.w;
        }
    }
    float p[4];
#pragma unroll
    for (int r = 0; r < 4; ++r) {
        float pv = fmaxf(fast_tanh(2.0f * (a1[r] - a2[r])), 0.0f);
        if (m == n0 + r) pv += 1.0f;
        p[r] = pv;
    }
    float sr[4] = {p[0], p[1], p[2], p[3]};
    for (int o = 32; o > 0; o >>= 1) {
#pragma unroll
        for (int r = 0; r < 4; ++r) sr[r] += __shfl_down(sr[r], o);
    }
    int wid = m >> 6, lane = m & 63;
    if (lane == 0) {
#pragma unroll
        for (int r = 0; r < 4; ++r) red[wid][r] = sr[r];
    }
    __syncthreads();
    if (m < 4) {
        float t = 0.f;
        for (int i = 0; i < 8; ++i) t += red[i][m];
        tot[m] = BETA_C * fast_rcp(t);
    }
    __syncthreads();
#pragma unroll
    for (int r = 0; r < 4; ++r)
        Mcomb[((size_t)b * N + n0 + r) * N + m] =
            GAMMA_C * A[(size_t)(n0 + r) * N + m] + p[r] * tot[r];
    if (m < 4 * CC) {
        int r = m / CC, k = m - r * CC;
        size_t nn = (size_t)b * N + n0 + r;
        float v;
        if (k < F) v = graph[(size_t)b * gstride + (size_t)(n0 + r) * F + k];
        else       v = hidden[nn * H + (k - F)];
        comb[nn * CC + k] = v;
    }
}

// ---------------------------------------------------------------------------
// zr5 / cup5: 16-row slabs (grid 512), 256 thr. Sums 8 rnn partials.
// ---------------------------------------------------------------------------
__device__ __forceinline__ void stage_xt(float (*Xt)[20], const float* __restrict__ base,
                                         const float* __restrict__ P1,
                                         const float* __restrict__ P2,
                                         size_t nn0, int tid)
{
    constexpr size_t psC = (size_t)B * N * CC;
    const float2* c2 = (const float2*)(base + nn0 * CC);
    const float2* p1b = (const float2*)(P1 + nn0 * CC);
    const float2* p2b = (const float2*)(P2 + nn0 * CC);
    for (int l = tid; l < 16 * 33; l += 256) {
        int row = l & 15, kp = l >> 4;       // kp 0..32
        int idx = row * 33 + kp;
        float2 v = c2[idx];
        Xt[2 * kp][row] = v.x; Xt[2 * kp + 1][row] = v.y;
        float2 a = p1b[idx];
#pragma unroll
        for (int j = 1; j < NPART; ++j) {
            float2 w = ((const float2*)(P1 + (size_t)j * psC + nn0 * CC))[idx];
            a.x += w.x; a.y += w.y;
        }
        Xt[66 + 2 * kp][row] = a.x; Xt[66 + 2 * kp + 1][row] = a.y;
        float2 c = p2b[idx];
#pragma unroll
        for (int j = 1; j < NPART; ++j) {
            float2 w = ((const float2*)(P2 + (size_t)j * psC + nn0 * CC))[idx];
            c.x += w.x; c.y += w.y;
        }
        Xt[132 + 2 * kp][row] = c.x; Xt[132 + 2 * kp + 1][row] = c.y;
    }
}

__global__ __launch_bounds__(256) void zr5_kernel(
    const float* __restrict__ comb, const float* __restrict__ P1, const float* __restrict__ P2,
    const float* __restrict__ Wgz, const float* __restrict__ bgz,
    const float* __restrict__ Wgr, const float* __restrict__ bgr,
    const float* __restrict__ hidden,
    float* __restrict__ z, float* __restrict__ comb2)
{
    __shared__ float Xt[198][20];
    __shared__ float Wl[66][128];
    const int tid = threadIdx.x;
    const size_t nn0 = (size_t)blockIdx.x * 16;

    stage_xt(Xt, comb, P1, P2, nn0, tid);

    const int cp = tid & 63;
    const int rg = tid >> 6;
    float2 bias = (cp < 32) ? *(const float2*)&bgz[2 * cp]
                            : *(const float2*)&bgr[2 * cp - 64];
    float acc[4][2];
#pragma unroll
    for (int r = 0; r < 4; ++r) { acc[r][0] = bias.x; acc[r][1] = bias.y; }

    for (int ch = 0; ch < 3; ++ch) {
        const int sk0 = ch * 66;
        for (int l = tid; l < 66 * 32; l += 256) {
            int j = l >> 5, q = l & 31;
            float4 w = (q < 16)
                ? ((const float4*)(Wgz + (size_t)(sk0 + j) * H))[q]
                : ((const float4*)(Wgr + (size_t)(sk0 + j) * H))[q - 16];
            *(float4*)&Wl[j][q << 2] = w;
        }
        __syncthreads();
#pragma unroll 6
        for (int j = 0; j < 66; ++j) {
            float4 xv = *(const float4*)&Xt[sk0 + j][rg << 2];
            float2 wv = *(const float2*)&Wl[j][cp << 1];
            acc[0][0] += xv.x * wv.x; acc[0][1] += xv.x * wv.y;
            acc[1][0] += xv.y * wv.x; acc[1][1] += xv.y * wv.y;
            acc[2][0] += xv.z * wv.x; acc[2][1] += xv.z * wv.y;
            acc[3][0] += xv.w * wv.x; acc[3][1] += xv.w * wv.y;
        }
        __syncthreads();
    }

    if (cp < 32) {
        const int oc = 2 * cp;
#pragma unroll
        for (int r = 0; r < 4; ++r) {
            size_t nn = nn0 + (rg << 2) + r;
            z[nn * H + oc]     = fast_sigmoid(acc[r][0]);
            z[nn * H + oc + 1] = fast_sigmoid(acc[r][1]);
        }
    } else {
        const int oc = 2 * cp - 64;
#pragma unroll
        for (int r = 0; r < 4; ++r) {
            size_t nn = nn0 + (rg << 2) + r;
            float h0 = hidden[nn * H + oc], h1 = hidden[nn * H + oc + 1];
            comb2[nn * CC + F + oc]     = fast_sigmoid(acc[r][0]) * h0;
            comb2[nn * CC + F + oc + 1] = fast_sigmoid(acc[r][1]) * h1;
        }
    }
    if (tid < 32) {
        int row = tid >> 1, f = tid & 1;
        comb2[(nn0 + row) * CC + f] = Xt[f][row];
    }
}

__global__ __launch_bounds__(256) void cup5_kernel(
    const float* __restrict__ comb2, const float* __restrict__ P1, const float* __restrict__ P2,
    const float* __restrict__ Wgc, const float* __restrict__ bgc,
    const float* __restrict__ z, float* __restrict__ hidden)
{
    __shared__ float Xt[198][20];
    __shared__ float Wl[66][64];
    const int tid = threadIdx.x;
    const size_t nn0 = (size_t)blockIdx.x * 16;

    stage_xt(Xt, comb2, P1, P2, nn0, tid);

    const int cp = tid & 31;
    const int rg = tid >> 5;
    float2 bias = *(const float2*)&bgc[2 * cp];
    float acc[2][2];
#pragma unroll
    for (int r = 0; r < 2; ++r) { acc[r][0] = bias.x; acc[r][1] = bias.y; }

    for (int ch = 0; ch < 3; ++ch) {
        const int sk0 = ch * 66;
        for (int l = tid; l < 66 * 16; l += 256) {
            int j = l >> 4, q = l & 15;
            float4 w = ((const float4*)(Wgc + (size_t)(sk0 + j) * H))[q];
            *(float4*)&Wl[j][q << 2] = w;
        }
        __syncthreads();
#pragma unroll 6
        for (int j = 0; j < 66; ++j) {
            float2 xv = *(const float2*)&Xt[sk0 + j][rg << 1];
            float2 wv = *(const float2*)&Wl[j][cp << 1];
            acc[0][0] += xv.x * wv.x; acc[0][1] += xv.x * wv.y;
            acc[1][0] += xv.y * wv.x; acc[1][1] += xv.y * wv.y;
        }
        __syncthreads();
    }

    const int oc = 2 * cp;
#pragma unroll
    for (int r = 0; r < 2; ++r) {
        size_t nn = nn0 + (rg << 1) + r;
        float cv0 = fast_tanh(acc[r][0]);
        float cv1 = fast_tanh(acc[r][1]);
        float zv0 = z[nn * H + oc],     ho0 = hidden[nn * H + oc];
        float zv1 = z[nn * H + oc + 1], ho1 = hidden[nn * H + oc + 1];
        hidden[nn * H + oc]     = zv0 * ho0 + (1.0f - zv0) * cv0;
        hidden[nn * H + oc + 1] = zv1 * ho1 + (1.0f - zv1) * cv1;
    }
}

// q/k precompute
__global__ void qk_kernel(const float* __restrict__ sample,
                          const float* __restrict__ wq, const float* __restrict__ wk,
                          const float* __restrict__ attn_bias,
                          float* __restrict__ q, float* __restrict__ kk)
{
    int idx = blockIdx.x * 256 + threadIdx.x;
    if (idx < B * N * DA) {
        int d = idx & 7;
        int n = (idx >> 3) & (N - 1);
        int b = idx >> 12;
        const float* tar = sample + (((size_t)b * T + (T - 1)) * N + n) * F;
        q[idx] = tar[0] * wq[d] + tar[1] * wq[DA + d] + attn_bias[d];
    } else {
        int j = idx - B * N * DA;
        int d = j & 7;
        int n = (j >> 3) & (N - 1);
        int t = (j >> 12) & 3;
        int b = j >> 14;
        const float* s = sample + (((size_t)b * T + (T - 4 + t)) * N + n) * F;
        kk[j] = s[0] * wk[d] + s[1] * wk[DA + d];
    }
}

// scores v3: grid (32, 64), 256 thr.
__global__ __launch_bounds__(256) void scores3_kernel(
    const float* __restrict__ q, const float* __restrict__ kk,
    const float* __restrict__ trans, float* __restrict__ attn)
{
    int bt = blockIdx.y;
    int b = bt >> 2;
    int rbase = blockIdx.x * 16;
    int wid = threadIdx.x >> 6, lane = threadIdx.x & 63;
    const float* kkbt = kk + (size_t)bt * N * DA;
    float* attnbt = attn + (size_t)bt * N * N;
    float tr[8];
#pragma unroll
    for (int d = 0; d < 8; ++d) tr[d] = trans[d];
    for (int i = 0; i < 4; ++i) {
        int n = rbase + wid * 4 + i;
        const float* qp = q + ((size_t)b * N + n) * DA;
        float4 qa = *(const float4*)qp, qb = *(const float4*)(qp + 4);
        float ev[8]; float ssum = 0.f;
#pragma unroll
        for (int k = 0; k < 8; ++k) {
            const float* kp = kkbt + (size_t)(k * 64 + lane) * DA;
            float4 ka = *(const float4*)kp, kb = *(const float4*)(kp + 4);
            float s = fast_tanh(qa.x + ka.x) * tr[0] + fast_tanh(qa.y + ka.y) * tr[1]
                    + fast_tanh(qa.z + ka.z) * tr[2] + fast_tanh(qa.w + ka.w) * tr[3]
                    + fast_tanh(qb.x + kb.x) * tr[4] + fast_tanh(qb.y + kb.y) * tr[5]
                    + fast_tanh(qb.z + kb.z) * tr[6] + fast_tanh(qb.w + kb.w) * tr[7];
            ev[k] = __expf(s);
            ssum += ev[k];
        }
        for (int o = 32; o > 0; o >>= 1) ssum += __shfl_down(ssum, o);
        ssum = __shfl(ssum, 0);
        float rinv = fast_rcp(ssum);
#pragma unroll
        for (int k = 0; k < 8; ++k)
            attnbt[(size_t)n * N + k * 64 + lane] = ev[k] * rinv;
    }
}

// TGN conv: grid (8, 64), 256 thr.
__global__ __launch_bounds__(256) void tgn2_kernel(
    const float* __restrict__ A, const float* __restrict__ attn,
    const float* __restrict__ hbase, long hsB, long hsT,
    const float* __restrict__ xbase, long xsB, long xsT,
    float* __restrict__ out)
{
    __shared__ float sh_m[64][65];
    __shared__ float sh_h[64][2];
    int bt = blockIdx.y;
    int w0 = blockIdx.x * 64;
    int tid = threadIdx.x;
    int wl = tid >> 2, c = tid & 1, vh = (tid >> 1) & 1;
    const float* hp = hbase + (size_t)(bt >> 2) * hsB + (size_t)(bt & 3) * hsT;
    const float* ap = attn + (size_t)bt * N * N;
    float acc = 0.f;
    for (int vt = 0; vt < 8; ++vt) {
        int v0 = vt * 64;
#pragma unroll
        for (int it = 0; it < 16; ++it) {
            int l = it * 256 + tid;
            int vr = l >> 6, wc = l & 63;
            size_t gi = (size_t)(v0 + vr) * N + (w0 + wc);
            sh_m[wc][vr] = A[gi] + ap[gi];
        }
        if (tid < 128) sh_h[tid >> 1][tid & 1] = hp[(size_t)(v0 + (tid >> 1)) * F + (tid & 1)];
        __syncthreads();
#pragma unroll
        for (int jj = 0; jj < 32; ++jj) {
            int j = vh * 32 + jj;
            acc += sh_m[wl][j] * sh_h[j][c];
        }
        __syncthreads();
    }
    acc += __shfl_xor(acc, 2);
    if (vh == 0) {
        const float* xp = xbase + (size_t)(bt >> 2) * xsB + (size_t)(bt & 3) * xsT;
        out[((size_t)bt * N + w0 + wl) * F + c] =
            ALPHA_C * xp[(size_t)(w0 + wl) * F + c] + GAMMA_C * acc;
    }
}

// tgn_out + gat fused: block = 8 rows x 32 oc, grid B*N/8.
__global__ __launch_bounds__(256) void tgn_out_gat_kernel(
    const float* __restrict__ sample,
    const float* __restrict__ th1, const float* __restrict__ th2,
    const float* __restrict__ Wt, const float* __restrict__ bt_,
    const float* __restrict__ Ws, const float* __restrict__ bs,
    float* __restrict__ tar32, float* __restrict__ out0)
{
    __shared__ float sh_t[8][33];
    const int tid = threadIdx.x;
    const int oc = tid & 31;
    const int r = tid >> 5;
    const size_t nn = (size_t)blockIdx.x * 8 + r;
    const int n = (int)(nn & (N - 1));
    const int b = (int)(nn >> 9);
    float acc = 0.f;
    for (int t = 0; t < 4; ++t) {
        int bt = b * 4 + t;
        const float* s = sample + (((size_t)b * T + (T - 4 + t)) * N + n) * F;
        size_t rr = ((size_t)bt * N + n) * F;
        float v = bt_[oc];
        v += s[0] * Wt[0 * TGN_OC + oc] + s[1] * Wt[1 * TGN_OC + oc];
        v += th1[rr] * Wt[2 * TGN_OC + oc] + th1[rr + 1] * Wt[3 * TGN_OC + oc];
        v += th2[rr] * Wt[4 * TGN_OC + oc] + th2[rr + 1] * Wt[5 * TGN_OC + oc];
        acc += fmaxf(v, 0.0f);
    }
    tar32[nn * TGN_OC + oc] = acc;
    sh_t[r][oc] = acc;
    __syncthreads();
    if (tid < 16) {
        int row = tid >> 1, f = tid & 1;
        size_t nn2 = (size_t)blockIdx.x * 8 + row;
        float g = bs[f];
#pragma unroll
        for (int k = 0; k < TGN_OC; ++k) g += sh_t[row][k] * Ws[(size_t)k * F + f];
        out0[nn2 * F + f] = g;
    }
}

__global__ void final_kernel(const float* __restrict__ hidden, const float* __restrict__ tar32,
                             const float* __restrict__ Wl, const float* __restrict__ bl,
                             const float* __restrict__ Wm, const float* __restrict__ bm,
                             float* __restrict__ dout_gru, float* __restrict__ dout_fin)
{
    int idx = blockIdx.x * 256 + threadIdx.x;
    int f = idx & 1;
    int nn = idx >> 1;
    const float* hp = hidden + (size_t)nn * H;
    const float* tp = tar32 + (size_t)nn * TGN_OC;
    float g = bl[f], fin = bm[f];
    for (int k = 0; k < H; ++k) g += hp[k] * Wl[(size_t)k * F + f];
    for (int k = 0; k < TGN_OC; ++k) fin += tp[k] * Wm[(size_t)k * F + f];
    for (int k = 0; k < H; ++k) fin += hp[k] * Wm[(size_t)(TGN_OC + k) * F + f];
    dout_gru[idx] = g;
    dout_fin[idx] = fin;
}

// ---------------------------------------------------------------------------
// Host side
// ---------------------------------------------------------------------------
namespace {
struct Ptrs {
    const float *sample, *A, *wq, *wk, *attn_bias, *attn_trans, *Wt, *bt_;
    const float *Wa1, *ba1, *Wa2, *ba2, *Wsrc, *bsrc, *Wtgt, *btgt;
    const float *Wgz, *bgz, *Wgr, *bgr, *Wgc, *bgc, *Wsh, *bsh, *Wl, *bl, *Wm, *bm;
    float *hidden, *nvs, *nvt, *Mcomb, *K1, *K2, *comb, *comb2, *z, *P1, *P2;
    float *q, *kk, *th1, *th2, *tar32;
};

void gru_step(hipStream_t stream, const Ptrs& p, const float* graph, long gstride)
{
    dim3 bg(8, NPART, B);   // 1024 blocks x 4 waves = 16 waves/CU (4 blk/CU)
    hyper4_kernel<<<bg, 256, 0, stream>>>(p.P1, p.P2, p.hidden, p.K1, p.K2);
    gsgt5_kernel<<<B * N / 16, 256, 0, stream>>>(
        p.hidden, p.P1, p.P2, p.Wa1, p.ba1, p.Wa2, p.ba2, graph, gstride,
        p.Wsrc, p.bsrc, p.Wtgt, p.btgt, p.nvs, p.nvt);
    adp3_kernel<<<dim3(N / 4, B), 512, 0, stream>>>(
        p.nvs, p.nvt, p.A, p.hidden, graph, gstride, p.Mcomb, p.comb);
    bmm4_kernel<false><<<bg, 256, 0, stream>>>(p.P1, p.comb, p.comb, p.Mcomb);
    bmm4_kernel<true><<<bg, 256, 0, stream>>>(p.P2, p.comb, p.P1, p.Mcomb);
    zr5_kernel<<<B * N / 16, 256, 0, stream>>>(
        p.comb, p.P1, p.P2, p.Wgz, p.bgz, p.Wgr, p.bgr, p.hidden, p.z, p.comb2);
    bmm4_kernel<false><<<bg, 256, 0, stream>>>(p.P1, p.comb2, p.comb2, p.Mcomb);
    bmm4_kernel<true><<<bg, 256, 0, stream>>>(p.P2, p.comb2, p.P1, p.Mcomb);
    cup5_kernel<<<B * N / 16, 256, 0, stream>>>(
        p.comb2, p.P1, p.P2, p.Wgc, p.bgc, p.z, p.hidden);
}
}  // namespace

extern "C" void kernel_launch(void* const* d_in, const int* in_sizes, int n_in,
                              void* d_out, int out_size, void* d_ws, size_t ws_size,
                              hipStream_t stream)
{
    (void)in_sizes; (void)n_in; (void)out_size; (void)ws_size;
    Ptrs p;
    p.sample = (const float*)d_in[0];
    p.A      = (const float*)d_in[1];
    p.wq     = (const float*)d_in[2];
    p.wk     = (const float*)d_in[3];
    p.attn_bias  = (const float*)d_in[4];
    p.attn_trans = (const float*)d_in[5];
    p.Wt  = (const float*)d_in[6];
    p.bt_ = (const float*)d_in[7];
    p.Wa1 = (const float*)d_in[8];
    p.ba1 = (const float*)d_in[9];
    p.Wa2 = (const float*)d_in[10];
    p.ba2 = (const float*)d_in[11];
    p.Wsrc = (const float*)d_in[12];
    p.bsrc = (const float*)d_in[13];
    p.Wtgt = (const float*)d_in[14];
    p.btgt = (const float*)d_in[15];
    p.Wgz = (const float*)d_in[16];
    p.bgz = (const float*)d_in[17];
    p.Wgr = (const float*)d_in[18];
    p.bgr = (const float*)d_in[19];
    p.Wgc = (const float*)d_in[20];
    p.bgc = (const float*)d_in[21];
    p.Wsh = (const float*)d_in[22];
    p.bsh = (const float*)d_in[23];
    p.Wl  = (const float*)d_in[24];
    p.bl  = (const float*)d_in[25];
    p.Wm  = (const float*)d_in[26];
    p.bm  = (const float*)d_in[27];

    float* ws = (float*)d_ws;
    size_t off = 0;
    auto alloc = [&](size_t nelem) { float* r = ws + off; off += nelem; return r; };
    p.hidden = alloc((size_t)B * N * H);
    p.nvs    = alloc((size_t)B * N * E);
    p.nvt    = alloc((size_t)B * N * E);
    p.Mcomb  = alloc((size_t)B * N * N);
    p.K1     = alloc((size_t)N * N);
    p.K2     = alloc((size_t)N * N);
    p.comb   = alloc((size_t)B * N * CC);
    p.comb2  = alloc((size_t)B * N * CC);
    p.z      = alloc((size_t)B * N * H);
    p.P1     = alloc((size_t)NPART * B * N * CC);
    p.P2     = alloc((size_t)NPART * B * N * CC);
    p.q      = alloc((size_t)B * N * DA);
    p.kk     = alloc((size_t)B * 4 * N * DA);
    p.th1    = alloc((size_t)B * 4 * N * F);
    p.th2    = alloc((size_t)B * 4 * N * F);
    p.tar32  = alloc((size_t)B * N * TGN_OC);

    float* out = (float*)d_out;
    float* out_gat = out;
    float* out_gru = out + (size_t)B * N * F;
    float* out_fin = out + (size_t)2 * B * N * F;
    float* out_attn = out + (size_t)3 * B * N * F;

    hipMemsetAsync(p.hidden, 0, (size_t)B * N * H * sizeof(float), stream);
    scaleA_kernel<<<N * N / 256, 256, 0, stream>>>(p.A, p.K1);
    k2_kernel<<<dim3(32, 32), 256, 0, stream>>>(p.A, p.K2);

    for (int i = 0; i < 5; ++i) {
        const float* graph = p.sample + (size_t)(4 * i) * N * F;
        gru_step(stream, p, graph, (long)T * N * F);
    }

    qk_kernel<<<(B * N * DA + B * 4 * N * DA) / 256, 256, 0, stream>>>(
        p.sample, p.wq, p.wk, p.attn_bias, p.q, p.kk);
    scores3_kernel<<<dim3(32, 64), 256, 0, stream>>>(p.q, p.kk, p.attn_trans, out_attn);

    const float* srcbase = p.sample + (size_t)(T - 4) * N * F;
    tgn2_kernel<<<dim3(8, 64), 256, 0, stream>>>(
        p.A, out_attn, srcbase, (long)T * N * F, (long)N * F,
        srcbase, (long)T * N * F, (long)N * F, p.th1);
    tgn2_kernel<<<dim3(8, 64), 256, 0, stream>>>(
        p.A, out_attn, p.th1, (long)4 * N * F, (long)N * F,
        srcbase, (long)T * N * F, (long)N * F, p.th2);
    tgn_out_gat_kernel<<<B * N / 8, 256, 0, stream>>>(
        p.sample, p.th1, p.th2, p.Wt, p.bt_, p.Wsh, p.bsh, p.tar32, out_gat);

    gru_step(stream, p, out_gat, (long)N * F);

    final_kernel<<<(B * N * F) / 256, 256, 0, stream>>>(
        p.hidden, p.tar32, p.Wl, p.bl, p.Wm, p.bm, out_gru, out_fin);
}

// Round 6
// 1264.889 us; speedup vs baseline: 1.1072x; 1.1072x over previous
//
#include <hip/hip_runtime.h>

#define ALPHA_C 0.05f
#define BETA_C  0.95f
#define GAMMA_C 0.95f

constexpr int B = 16, T = 24, N = 512, F = 2, H = 64, E = 16;
constexpr int DA = 8;
constexpr int CC = F + H;    // 66
constexpr int TGN_OC = 32;
constexpr int NPART = 4;     // v-quarter partials

__device__ __forceinline__ float fast_rcp(float x) { return __builtin_amdgcn_rcpf(x); }
__device__ __forceinline__ float fast_tanh(float x) {
    return 1.0f - 2.0f * fast_rcp(__expf(2.0f * x) + 1.0f);
}
__device__ __forceinline__ float fast_sigmoid(float x) {
    return fast_rcp(1.0f + __expf(-x));
}

// async global->LDS, 16B per lane; lds ptr must be wave-uniform (HW adds lane*16).
__device__ __forceinline__ void gload16(const float* g, float* l)
{
    __builtin_amdgcn_global_load_lds((const __attribute__((address_space(1))) void*)g,
                                     (__attribute__((address_space(3))) void*)l, 16, 0, 0);
}

// K1 = GAMMA*A (one-time)
__global__ void scaleA_kernel(const float* __restrict__ A, float* __restrict__ K1)
{
    int i = blockIdx.x * 256 + threadIdx.x;
    K1[i] = GAMMA_C * A[i];
}

// K2 = GAMMA*ALPHA*A + GAMMA^2 * A@A (one-time). Grid (32,32), 256 thr.
__global__ __launch_bounds__(256) void k2_kernel(const float* __restrict__ A,
                                                 float* __restrict__ K2)
{
    __shared__ float rows[16][258];
    __shared__ float cols[256][17];
    const int tid = threadIdx.x;
    const int r0 = blockIdx.y * 16, c0 = blockIdx.x * 16;
    const int rr = tid >> 4, cc = tid & 15;
    float acc = 0.f;
    for (int k0 = 0; k0 < N; k0 += 256) {
#pragma unroll
        for (int it = 0; it < 4; ++it) {
            int l = it * 256 + tid;
            int row = l >> 6, k4 = (l & 63) << 2;
            *(float4*)&rows[row][k4] = *(const float4*)(A + (size_t)(r0 + row) * N + k0 + k4);
        }
#pragma unroll
        for (int it = 0; it < 4; ++it) {
            int l = it * 256 + tid;
            int k = l >> 2, c4 = (l & 3) << 2;
            *(float4*)&cols[k][c4] = *(const float4*)(A + (size_t)(k0 + k) * N + c0 + c4);
        }
        __syncthreads();
#pragma unroll 8
        for (int k = 0; k < 256; ++k) acc += rows[rr][k] * cols[k][cc];
        __syncthreads();
    }
    size_t i = (size_t)(r0 + rr) * N + c0 + cc;
    K2[i] = GAMMA_C * ALPHA_C * A[i] + GAMMA_C * GAMMA_C * acc;
}

// ---------------------------------------------------------------------------
// bmm4 (rnn path): 512 thr, 2x4 tile, grid (8,4,B) = 512 blocks.
// M tile (128x64) staged once upfront via async global_load_lds (overlaps the
// VGPR-staged h tile). 3 barriers. LDS 49.4 KB -> 3 blocks/CU.
// out_part[vq][b,w,c] = (vq==0 ? ALPHA*x : 0) + sum_{v in quarter} M[v,w]*in[b,v,c]
// ---------------------------------------------------------------------------
template<bool INSUM>
__global__ __launch_bounds__(512) void bmm4_kernel(
    float* __restrict__ out, const float* __restrict__ x, const float* __restrict__ in,
    const float* __restrict__ M)
{
    __shared__ float sh_m[128][64];   // packed; reads are row-local (no conflict)
    __shared__ float sh_h[64][68];
    constexpr int Crow = CC;          // 66
    const size_t pstr = (size_t)B * N * Crow;
    const int tid = threadIdx.x;
    const int b = blockIdx.z, w0 = blockIdx.x * 64, vq = blockIdx.y;
    const int cg = tid & 15;          // 4 cols
    const int wg = tid >> 4;          // 0..31: 2 w rows
    const int wid = tid >> 6;         // wave id 0..7
    const int lane = tid & 63;

    float acc[2][4] = {{0,0,0,0},{0,0,0,0}};
    float ag[2] = {0.f, 0.f};

    const float* Mb = M + (size_t)b * N * N + (size_t)(vq * 128) * N + w0;
    const float* inb = in + (size_t)b * N * Crow;

    // async stage full M tile: rows vq*128..+127, cols w0..w0+63 (linear LDS)
#pragma unroll
    for (int it = 0; it < 4; ++it) {
        int row = it * 32 + wid * 4 + (lane >> 4);
        gload16(Mb + (size_t)row * N + ((lane & 15) << 2),
                &sh_m[0][0] + (it * 2048 + wid * 256));
    }

    for (int vt = 0; vt < 2; ++vt) {
        const int v0 = vq * 128 + vt * 64;
        {
            const float2* h0 = (const float2*)(inb + (size_t)v0 * Crow);
            for (int l = tid; l < 64 * 33; l += 512) {
                int row = l / 33, k = (l - row * 33) * 2;
                float2 v = h0[l];
                if (INSUM) {
#pragma unroll
                    for (int j = 1; j < NPART; ++j) {
                        float2 w = ((const float2*)(inb + (size_t)j * pstr + (size_t)v0 * Crow))[l];
                        v.x += w.x; v.y += w.y;
                    }
                }
                *(float2*)&sh_h[row][k] = v;
            }
        }
        __syncthreads();
#pragma unroll 8
        for (int j = 0; j < 64; ++j) {
            float2 mv = *(const float2*)&sh_m[vt * 64 + j][wg << 1];
            float4 hv = *(const float4*)&sh_h[j][cg << 2];
            acc[0][0] += mv.x * hv.x; acc[0][1] += mv.x * hv.y;
            acc[0][2] += mv.x * hv.z; acc[0][3] += mv.x * hv.w;
            acc[1][0] += mv.y * hv.x; acc[1][1] += mv.y * hv.y;
            acc[1][2] += mv.y * hv.z; acc[1][3] += mv.y * hv.w;
            if (cg < 2) {
                float gv = sh_h[j][64 + cg];
                ag[0] += mv.x * gv; ag[1] += mv.y * gv;
            }
        }
        if (vt == 0) __syncthreads();   // protect sh_h before restaging
    }
    float* outp = out + (size_t)vq * pstr + (size_t)b * N * Crow;
    const float* xb = x + (size_t)b * N * Crow;
#pragma unroll
    for (int r = 0; r < 2; ++r) {
        const int w = w0 + (wg << 1) + r;
        const size_t base = (size_t)w * Crow + (cg << 2);
        float o0 = acc[r][0], o1 = acc[r][1], o2 = acc[r][2], o3 = acc[r][3];
        if (vq == 0) {
            o0 += ALPHA_C * xb[base];     o1 += ALPHA_C * xb[base + 1];
            o2 += ALPHA_C * xb[base + 2]; o3 += ALPHA_C * xb[base + 3];
        }
        float2 lo = {o0, o1}, hi = {o2, o3};
        *(float2*)(outp + base) = lo;
        *(float2*)(outp + base + 2) = hi;
        if (cg < 2) {
            size_t gb = (size_t)w * Crow + 64 + cg;
            float v = ag[r];
            if (vq == 0) v += ALPHA_C * xb[gb];
            outp[gb] = v;
        }
    }
}

// ---------------------------------------------------------------------------
// hyper5: fused K1+K2 at 512 thr, grid (8,4,B). All three tiles staged via
// async global_load_lds into packed [64][64] (reads row-local -> no conflicts).
// Per j: 2x b64 + 1x b128 for 16 FMA. LDS 48 KB -> 3 blocks/CU.
// ---------------------------------------------------------------------------
__global__ __launch_bounds__(512) void hyper5_kernel(
    float* __restrict__ P1, float* __restrict__ P2, const float* __restrict__ hidden,
    const float* __restrict__ K1, const float* __restrict__ K2)
{
    __shared__ float sh_m1[64][64];
    __shared__ float sh_m2[64][64];
    __shared__ float sh_h[64][64];
    const size_t pstr = (size_t)B * N * H;
    const int tid = threadIdx.x;
    const int b = blockIdx.z, w0 = blockIdx.x * 64, vq = blockIdx.y;
    const int cg = tid & 15;
    const int wg = tid >> 4;    // 0..31
    const int wid = tid >> 6;
    const int lane = tid & 63;

    float a1[2][4] = {{0,0,0,0},{0,0,0,0}};
    float a2[2][4] = {{0,0,0,0},{0,0,0,0}};
    const float* inb = hidden + (size_t)b * N * H;

    for (int vt = 0; vt < 2; ++vt) {
        const int v0 = vq * 128 + vt * 64;
#pragma unroll
        for (int it = 0; it < 2; ++it) {
            int row = it * 32 + wid * 4 + (lane >> 4);
            int c4 = (lane & 15) << 2;
            int loff = it * 2048 + wid * 256;
            gload16(K1 + (size_t)(v0 + row) * N + w0 + c4, &sh_m1[0][0] + loff);
            gload16(K2 + (size_t)(v0 + row) * N + w0 + c4, &sh_m2[0][0] + loff);
            gload16(inb + (size_t)(v0 + row) * H + c4,     &sh_h[0][0]  + loff);
        }
        __syncthreads();
#pragma unroll 8
        for (int j = 0; j < 64; ++j) {
            float2 m1 = *(const float2*)&sh_m1[j][wg << 1];
            float2 m2 = *(const float2*)&sh_m2[j][wg << 1];
            float4 hv = *(const float4*)&sh_h[j][cg << 2];
            a1[0][0] += m1.x * hv.x; a1[0][1] += m1.x * hv.y;
            a1[0][2] += m1.x * hv.z; a1[0][3] += m1.x * hv.w;
            a1[1][0] += m1.y * hv.x; a1[1][1] += m1.y * hv.y;
            a1[1][2] += m1.y * hv.z; a1[1][3] += m1.y * hv.w;
            a2[0][0] += m2.x * hv.x; a2[0][1] += m2.x * hv.y;
            a2[0][2] += m2.x * hv.z; a2[0][3] += m2.x * hv.w;
            a2[1][0] += m2.y * hv.x; a2[1][1] += m2.y * hv.y;
            a2[1][2] += m2.y * hv.z; a2[1][3] += m2.y * hv.w;
        }
        __syncthreads();
    }
    float* o1 = P1 + (size_t)vq * pstr + (size_t)b * N * H;
    float* o2 = P2 + (size_t)vq * pstr + (size_t)b * N * H;
#pragma unroll
    for (int r = 0; r < 2; ++r) {
        const int w = w0 + (wg << 1) + r;
        const size_t base = (size_t)w * H + (cg << 2);
        float4 v1 = {a1[r][0], a1[r][1], a1[r][2], a1[r][3]};
        float4 v2 = {a2[r][0], a2[r][1], a2[r][2], a2[r][3]};
        if (vq == 0) {
            float4 xv = *(const float4*)(inb + base);
            v1.x += ALPHA_C * xv.x; v1.y += ALPHA_C * xv.y;
            v1.z += ALPHA_C * xv.z; v1.w += ALPHA_C * xv.w;
            v2.x += ALPHA_C * xv.x; v2.y += ALPHA_C * xv.y;
            v2.z += ALPHA_C * xv.z; v2.w += ALPHA_C * xv.w;
        }
        *(float4*)(o1 + base) = v1;
        *(float4*)(o2 + base) = v2;
    }
}

// ---------------------------------------------------------------------------
// gsgt5: 16-row slabs (grid 512), 256 thr.
// ---------------------------------------------------------------------------
__global__ __launch_bounds__(256) void gsgt5_kernel(
    const float* __restrict__ hidden, const float* __restrict__ P1, const float* __restrict__ P2,
    const float* __restrict__ Wa1, const float* __restrict__ ba1,
    const float* __restrict__ Wa2, const float* __restrict__ ba2,
    const float* __restrict__ graph, long gstride,
    const float* __restrict__ Wsrc, const float* __restrict__ bsrc,
    const float* __restrict__ Wtgt, const float* __restrict__ btgt,
    float* __restrict__ nv_s, float* __restrict__ nv_t)
{
    constexpr size_t psH = (size_t)B * N * H;
    __shared__ float sh[16][196];
    __shared__ float W1t[16][196];
    __shared__ float W2t[16][196];
    const int tid = threadIdx.x;
    const int e = tid & 15;
    const int row = tid >> 4;
    const size_t nn0 = (size_t)blockIdx.x * 16;
    {
        int f4 = ((int)(nn0) + row) * 16 + e;
        float4 v = ((const float4*)hidden)[f4];
        *(float4*)&sh[row][e << 2] = v;
        float4 a = ((const float4*)P1)[f4];
#pragma unroll
        for (int j = 1; j < NPART; ++j) {
            float4 w = ((const float4*)(P1 + (size_t)j * psH))[f4];
            a.x += w.x; a.y += w.y; a.z += w.z; a.w += w.w;
        }
        *(float4*)&sh[row][64 + (e << 2)] = a;
        float4 c = ((const float4*)P2)[f4];
#pragma unroll
        for (int j = 1; j < NPART; ++j) {
            float4 w = ((const float4*)(P2 + (size_t)j * psH))[f4];
            c.x += w.x; c.y += w.y; c.z += w.z; c.w += w.w;
        }
        *(float4*)&sh[row][128 + (e << 2)] = c;
    }
    for (int l = tid; l < 768; l += 256) {
        int sk = l >> 2, q = l & 3;
        float4 w1 = ((const float4*)Wa1)[l];
        float4 w2 = ((const float4*)Wa2)[l];
        W1t[4 * q + 0][sk] = w1.x; W1t[4 * q + 1][sk] = w1.y;
        W1t[4 * q + 2][sk] = w1.z; W1t[4 * q + 3][sk] = w1.w;
        W2t[4 * q + 0][sk] = w2.x; W2t[4 * q + 1][sk] = w2.y;
        W2t[4 * q + 2][sk] = w2.z; W2t[4 * q + 3][sk] = w2.w;
    }
    __syncthreads();
    float gs = ba1[e], gt = ba2[e];
#pragma unroll 8
    for (int sk = 0; sk < 192; sk += 4) {
        float4 xv = *(const float4*)&sh[row][sk];
        float4 w1 = *(const float4*)&W1t[e][sk];
        float4 w2 = *(const float4*)&W2t[e][sk];
        gs += xv.x * w1.x + xv.y * w1.y + xv.z * w1.z + xv.w * w1.w;
        gt += xv.x * w2.x + xv.y * w2.y + xv.z * w2.z + xv.w * w2.w;
    }
    size_t nn = nn0 + row;
    int b = (int)(nn >> 9), n = (int)(nn & (N - 1));
    const float* g = graph + (size_t)b * gstride + (size_t)n * F;
    float g0 = g[0], g1 = g[1];
    float es = g0 * Wsrc[e] + g1 * Wsrc[E + e] + bsrc[e];
    float et = g0 * Wtgt[e] + g1 * Wtgt[E + e] + btgt[e];
    nv_s[nn * E + e] = fast_tanh(2.0f * es * gs);
    nv_t[nn * E + e] = fast_tanh(2.0f * et * gt);
}

// ---------------------------------------------------------------------------
// adp: 4 rows/block, grid (128,16), 512 thr.
// ---------------------------------------------------------------------------
__global__ __launch_bounds__(512) void adp3_kernel(
    const float* __restrict__ nv_s, const float* __restrict__ nv_t,
    const float* __restrict__ A,
    const float* __restrict__ hidden, const float* __restrict__ graph, long gstride,
    float* __restrict__ Mcomb, float* __restrict__ comb)
{
    __shared__ float red[8][4];
    __shared__ float tot[4];
    const int m = threadIdx.x;
    const int n0 = blockIdx.x * 4;
    const int b = blockIdx.y;
    const float4* sm = (const float4*)(nv_s + ((size_t)b * N + m) * E);
    const float4* tm = (const float4*)(nv_t + ((size_t)b * N + m) * E);
    const float4* sn = (const float4*)(nv_s + ((size_t)b * N + n0) * E);
    const float4* tn = (const float4*)(nv_t + ((size_t)b * N + n0) * E);
    float a1[4] = {0.f,0.f,0.f,0.f}, a2[4] = {0.f,0.f,0.f,0.f};
#pragma unroll
    for (int dd = 0; dd < 4; ++dd) {
        float4 smv = sm[dd], tmv = tm[dd];
#pragma unroll
        for (int r = 0; r < 4; ++r) {
            float4 snv = sn[r * 4 + dd], tnv = tn[r * 4 + dd];
            a1[r] += snv.x * tmv.x + snv.y * tmv.y + snv.z * tmv.z + snv.w * tmv.w;
            a2[r] += tnv.x * smv.x + tnv.y * smv.y + tnv.z * smv.z + tnv.w * smv.w;
        }
    }
    float p[4];
#pragma unroll
    for (int r = 0; r < 4; ++r) {
        float pv = fmaxf(fast_tanh(2.0f * (a1[r] - a2[r])), 0.0f);
        if (m == n0 + r) pv += 1.0f;
        p[r] = pv;
    }
    float sr[4] = {p[0], p[1], p[2], p[3]};
    for (int o = 32; o > 0; o >>= 1) {
#pragma unroll
        for (int r = 0; r < 4; ++r) sr[r] += __shfl_down(sr[r], o);
    }
    int wid = m >> 6, lane = m & 63;
    if (lane == 0) {
#pragma unroll
        for (int r = 0; r < 4; ++r) red[wid][r] = sr[r];
    }
    __syncthreads();
    if (m < 4) {
        float t = 0.f;
        for (int i = 0; i < 8; ++i) t += red[i][m];
        tot[m] = BETA_C * fast_rcp(t);
    }
    __syncthreads();
#pragma unroll
    for (int r = 0; r < 4; ++r)
        Mcomb[((size_t)b * N + n0 + r) * N + m] =
            GAMMA_C * A[(size_t)(n0 + r) * N + m] + p[r] * tot[r];
    if (m < 4 * CC) {
        int r = m / CC, k = m - r * CC;
        size_t nn = (size_t)b * N + n0 + r;
        float v;
        if (k < F) v = graph[(size_t)b * gstride + (size_t)(n0 + r) * F + k];
        else       v = hidden[nn * H + (k - F)];
        comb[nn * CC + k] = v;
    }
}

// ---------------------------------------------------------------------------
// zr5 / cup5: 16-row slabs (grid 512), 256 thr.
// ---------------------------------------------------------------------------
__device__ __forceinline__ void stage_xt(float (*Xt)[20], const float* __restrict__ base,
                                         const float* __restrict__ P1,
                                         const float* __restrict__ P2,
                                         size_t nn0, int tid)
{
    constexpr size_t psC = (size_t)B * N * CC;
    const float2* c2 = (const float2*)(base + nn0 * CC);
    const float2* p1b = (const float2*)(P1 + nn0 * CC);
    const float2* p2b = (const float2*)(P2 + nn0 * CC);
    for (int l = tid; l < 16 * 33; l += 256) {
        int row = l & 15, kp = l >> 4;       // kp 0..32
        int idx = row * 33 + kp;
        float2 v = c2[idx];
        Xt[2 * kp][row] = v.x; Xt[2 * kp + 1][row] = v.y;
        float2 a = p1b[idx];
#pragma unroll
        for (int j = 1; j < NPART; ++j) {
            float2 w = ((const float2*)(P1 + (size_t)j * psC + nn0 * CC))[idx];
            a.x += w.x; a.y += w.y;
        }
        Xt[66 + 2 * kp][row] = a.x; Xt[66 + 2 * kp + 1][row] = a.y;
        float2 c = p2b[idx];
#pragma unroll
        for (int j = 1; j < NPART; ++j) {
            float2 w = ((const float2*)(P2 + (size_t)j * psC + nn0 * CC))[idx];
            c.x += w.x; c.y += w.y;
        }
        Xt[132 + 2 * kp][row] = c.x; Xt[132 + 2 * kp + 1][row] = c.y;
    }
}

__global__ __launch_bounds__(256) void zr5_kernel(
    const float* __restrict__ comb, const float* __restrict__ P1, const float* __restrict__ P2,
    const float* __restrict__ Wgz, const float* __restrict__ bgz,
    const float* __restrict__ Wgr, const float* __restrict__ bgr,
    const float* __restrict__ hidden,
    float* __restrict__ z, float* __restrict__ comb2)
{
    __shared__ float Xt[198][20];
    __shared__ float Wl[66][128];
    const int tid = threadIdx.x;
    const size_t nn0 = (size_t)blockIdx.x * 16;

    stage_xt(Xt, comb, P1, P2, nn0, tid);

    const int cp = tid & 63;
    const int rg = tid >> 6;
    float2 bias = (cp < 32) ? *(const float2*)&bgz[2 * cp]
                            : *(const float2*)&bgr[2 * cp - 64];
    float acc[4][2];
#pragma unroll
    for (int r = 0; r < 4; ++r) { acc[r][0] = bias.x; acc[r][1] = bias.y; }

    for (int ch = 0; ch < 3; ++ch) {
        const int sk0 = ch * 66;
        for (int l = tid; l < 66 * 32; l += 256) {
            int j = l >> 5, q = l & 31;
            float4 w = (q < 16)
                ? ((const float4*)(Wgz + (size_t)(sk0 + j) * H))[q]
                : ((const float4*)(Wgr + (size_t)(sk0 + j) * H))[q - 16];
            *(float4*)&Wl[j][q << 2] = w;
        }
        __syncthreads();
#pragma unroll 6
        for (int j = 0; j < 66; ++j) {
            float4 xv = *(const float4*)&Xt[sk0 + j][rg << 2];
            float2 wv = *(const float2*)&Wl[j][cp << 1];
            acc[0][0] += xv.x * wv.x; acc[0][1] += xv.x * wv.y;
            acc[1][0] += xv.y * wv.x; acc[1][1] += xv.y * wv.y;
            acc[2][0] += xv.z * wv.x; acc[2][1] += xv.z * wv.y;
            acc[3][0] += xv.w * wv.x; acc[3][1] += xv.w * wv.y;
        }
        __syncthreads();
    }

    if (cp < 32) {
        const int oc = 2 * cp;
#pragma unroll
        for (int r = 0; r < 4; ++r) {
            size_t nn = nn0 + (rg << 2) + r;
            z[nn * H + oc]     = fast_sigmoid(acc[r][0]);
            z[nn * H + oc + 1] = fast_sigmoid(acc[r][1]);
        }
    } else {
        const int oc = 2 * cp - 64;
#pragma unroll
        for (int r = 0; r < 4; ++r) {
            size_t nn = nn0 + (rg << 2) + r;
            float h0 = hidden[nn * H + oc], h1 = hidden[nn * H + oc + 1];
            comb2[nn * CC + F + oc]     = fast_sigmoid(acc[r][0]) * h0;
            comb2[nn * CC + F + oc + 1] = fast_sigmoid(acc[r][1]) * h1;
        }
    }
    if (tid < 32) {
        int row = tid >> 1, f = tid & 1;
        comb2[(nn0 + row) * CC + f] = Xt[f][row];
    }
}

__global__ __launch_bounds__(256) void cup5_kernel(
    const float* __restrict__ comb2, const float* __restrict__ P1, const float* __restrict__ P2,
    const float* __restrict__ Wgc, const float* __restrict__ bgc,
    const float* __restrict__ z, float* __restrict__ hidden)
{
    __shared__ float Xt[198][20];
    __shared__ float Wl[66][64];
    const int tid = threadIdx.x;
    const size_t nn0 = (size_t)blockIdx.x * 16;

    stage_xt(Xt, comb2, P1, P2, nn0, tid);

    const int cp = tid & 31;
    const int rg = tid >> 5;
    float2 bias = *(const float2*)&bgc[2 * cp];
    float acc[2][2];
#pragma unroll
    for (int r = 0; r < 2; ++r) { acc[r][0] = bias.x; acc[r][1] = bias.y; }

    for (int ch = 0; ch < 3; ++ch) {
        const int sk0 = ch * 66;
        for (int l = tid; l < 66 * 16; l += 256) {
            int j = l >> 4, q = l & 15;
            float4 w = ((const float4*)(Wgc + (size_t)(sk0 + j) * H))[q];
            *(float4*)&Wl[j][q << 2] = w;
        }
        __syncthreads();
#pragma unroll 6
        for (int j = 0; j < 66; ++j) {
            float2 xv = *(const float2*)&Xt[sk0 + j][rg << 1];
            float2 wv = *(const float2*)&Wl[j][cp << 1];
            acc[0][0] += xv.x * wv.x; acc[0][1] += xv.x * wv.y;
            acc[1][0] += xv.y * wv.x; acc[1][1] += xv.y * wv.y;
        }
        __syncthreads();
    }

    const int oc = 2 * cp;
#pragma unroll
    for (int r = 0; r < 2; ++r) {
        size_t nn = nn0 + (rg << 1) + r;
        float cv0 = fast_tanh(acc[r][0]);
        float cv1 = fast_tanh(acc[r][1]);
        float zv0 = z[nn * H + oc],     ho0 = hidden[nn * H + oc];
        float zv1 = z[nn * H + oc + 1], ho1 = hidden[nn * H + oc + 1];
        hidden[nn * H + oc]     = zv0 * ho0 + (1.0f - zv0) * cv0;
        hidden[nn * H + oc + 1] = zv1 * ho1 + (1.0f - zv1) * cv1;
    }
}

// q/k precompute
__global__ void qk_kernel(const float* __restrict__ sample,
                          const float* __restrict__ wq, const float* __restrict__ wk,
                          const float* __restrict__ attn_bias,
                          float* __restrict__ q, float* __restrict__ kk)
{
    int idx = blockIdx.x * 256 + threadIdx.x;
    if (idx < B * N * DA) {
        int d = idx & 7;
        int n = (idx >> 3) & (N - 1);
        int b = idx >> 12;
        const float* tar = sample + (((size_t)b * T + (T - 1)) * N + n) * F;
        q[idx] = tar[0] * wq[d] + tar[1] * wq[DA + d] + attn_bias[d];
    } else {
        int j = idx - B * N * DA;
        int d = j & 7;
        int n = (j >> 3) & (N - 1);
        int t = (j >> 12) & 3;
        int b = j >> 14;
        const float* s = sample + (((size_t)b * T + (T - 4 + t)) * N + n) * F;
        kk[j] = s[0] * wk[d] + s[1] * wk[DA + d];
    }
}

// scores v3: grid (32, 64), 256 thr.
__global__ __launch_bounds__(256) void scores3_kernel(
    const float* __restrict__ q, const float* __restrict__ kk,
    const float* __restrict__ trans, float* __restrict__ attn)
{
    int bt = blockIdx.y;
    int b = bt >> 2;
    int rbase = blockIdx.x * 16;
    int wid = threadIdx.x >> 6, lane = threadIdx.x & 63;
    const float* kkbt = kk + (size_t)bt * N * DA;
    float* attnbt = attn + (size_t)bt * N * N;
    float tr[8];
#pragma unroll
    for (int d = 0; d < 8; ++d) tr[d] = trans[d];
    for (int i = 0; i < 4; ++i) {
        int n = rbase + wid * 4 + i;
        const float* qp = q + ((size_t)b * N + n) * DA;
        float4 qa = *(const float4*)qp, qb = *(const float4*)(qp + 4);
        float ev[8]; float ssum = 0.f;
#pragma unroll
        for (int k = 0; k < 8; ++k) {
            const float* kp = kkbt + (size_t)(k * 64 + lane) * DA;
            float4 ka = *(const float4*)kp, kb = *(const float4*)(kp + 4);
            float s = fast_tanh(qa.x + ka.x) * tr[0] + fast_tanh(qa.y + ka.y) * tr[1]
                    + fast_tanh(qa.z + ka.z) * tr[2] + fast_tanh(qa.w + ka.w) * tr[3]
                    + fast_tanh(qb.x + kb.x) * tr[4] + fast_tanh(qb.y + kb.y) * tr[5]
                    + fast_tanh(qb.z + kb.z) * tr[6] + fast_tanh(qb.w + kb.w) * tr[7];
            ev[k] = __expf(s);
            ssum += ev[k];
        }
        for (int o = 32; o > 0; o >>= 1) ssum += __shfl_down(ssum, o);
        ssum = __shfl(ssum, 0);
        float rinv = fast_rcp(ssum);
#pragma unroll
        for (int k = 0; k < 8; ++k)
            attnbt[(size_t)n * N + k * 64 + lane] = ev[k] * rinv;
    }
}

// TGN conv: grid (8, 64), 256 thr.
__global__ __launch_bounds__(256) void tgn2_kernel(
    const float* __restrict__ A, const float* __restrict__ attn,
    const float* __restrict__ hbase, long hsB, long hsT,
    const float* __restrict__ xbase, long xsB, long xsT,
    float* __restrict__ out)
{
    __shared__ float sh_m[64][65];
    __shared__ float sh_h[64][2];
    int bt = blockIdx.y;
    int w0 = blockIdx.x * 64;
    int tid = threadIdx.x;
    int wl = tid >> 2, c = tid & 1, vh = (tid >> 1) & 1;
    const float* hp = hbase + (size_t)(bt >> 2) * hsB + (size_t)(bt & 3) * hsT;
    const float* ap = attn + (size_t)bt * N * N;
    float acc = 0.f;
    for (int vt = 0; vt < 8; ++vt) {
        int v0 = vt * 64;
#pragma unroll
        for (int it = 0; it < 16; ++it) {
            int l = it * 256 + tid;
            int vr = l >> 6, wc = l & 63;
            size_t gi = (size_t)(v0 + vr) * N + (w0 + wc);
            sh_m[wc][vr] = A[gi] + ap[gi];
        }
        if (tid < 128) sh_h[tid >> 1][tid & 1] = hp[(size_t)(v0 + (tid >> 1)) * F + (tid & 1)];
        __syncthreads();
#pragma unroll
        for (int jj = 0; jj < 32; ++jj) {
            int j = vh * 32 + jj;
            acc += sh_m[wl][j] * sh_h[j][c];
        }
        __syncthreads();
    }
    acc += __shfl_xor(acc, 2);
    if (vh == 0) {
        const float* xp = xbase + (size_t)(bt >> 2) * xsB + (size_t)(bt & 3) * xsT;
        out[((size_t)bt * N + w0 + wl) * F + c] =
            ALPHA_C * xp[(size_t)(w0 + wl) * F + c] + GAMMA_C * acc;
    }
}

// tgn_out + gat fused: block = 8 rows x 32 oc, grid B*N/8.
__global__ __launch_bounds__(256) void tgn_out_gat_kernel(
    const float* __restrict__ sample,
    const float* __restrict__ th1, const float* __restrict__ th2,
    const float* __restrict__ Wt, const float* __restrict__ bt_,
    const float* __restrict__ Ws, const float* __restrict__ bs,
    float* __restrict__ tar32, float* __restrict__ out0)
{
    __shared__ float sh_t[8][33];
    const int tid = threadIdx.x;
    const int oc = tid & 31;
    const int r = tid >> 5;
    const size_t nn = (size_t)blockIdx.x * 8 + r;
    const int n = (int)(nn & (N - 1));
    const int b = (int)(nn >> 9);
    float acc = 0.f;
    for (int t = 0; t < 4; ++t) {
        int bt = b * 4 + t;
        const float* s = sample + (((size_t)b * T + (T - 4 + t)) * N + n) * F;
        size_t rr = ((size_t)bt * N + n) * F;
        float v = bt_[oc];
        v += s[0] * Wt[0 * TGN_OC + oc] + s[1] * Wt[1 * TGN_OC + oc];
        v += th1[rr] * Wt[2 * TGN_OC + oc] + th1[rr + 1] * Wt[3 * TGN_OC + oc];
        v += th2[rr] * Wt[4 * TGN_OC + oc] + th2[rr + 1] * Wt[5 * TGN_OC + oc];
        acc += fmaxf(v, 0.0f);
    }
    tar32[nn * TGN_OC + oc] = acc;
    sh_t[r][oc] = acc;
    __syncthreads();
    if (tid < 16) {
        int row = tid >> 1, f = tid & 1;
        size_t nn2 = (size_t)blockIdx.x * 8 + row;
        float g = bs[f];
#pragma unroll
        for (int k = 0; k < TGN_OC; ++k) g += sh_t[row][k] * Ws[(size_t)k * F + f];
        out0[nn2 * F + f] = g;
    }
}

__global__ void final_kernel(const float* __restrict__ hidden, const float* __restrict__ tar32,
                             const float* __restrict__ Wl, const float* __restrict__ bl,
                             const float* __restrict__ Wm, const float* __restrict__ bm,
                             float* __restrict__ dout_gru, float* __restrict__ dout_fin)
{
    int idx = blockIdx.x * 256 + threadIdx.x;
    int f = idx & 1;
    int nn = idx >> 1;
    const float* hp = hidden + (size_t)nn * H;
    const float* tp = tar32 + (size_t)nn * TGN_OC;
    float g = bl[f], fin = bm[f];
    for (int k = 0; k < H; ++k) g += hp[k] * Wl[(size_t)k * F + f];
    for (int k = 0; k < TGN_OC; ++k) fin += tp[k] * Wm[(size_t)k * F + f];
    for (int k = 0; k < H; ++k) fin += hp[k] * Wm[(size_t)(TGN_OC + k) * F + f];
    dout_gru[idx] = g;
    dout_fin[idx] = fin;
}

// ---------------------------------------------------------------------------
// Host side
// ---------------------------------------------------------------------------
namespace {
struct Ptrs {
    const float *sample, *A, *wq, *wk, *attn_bias, *attn_trans, *Wt, *bt_;
    const float *Wa1, *ba1, *Wa2, *ba2, *Wsrc, *bsrc, *Wtgt, *btgt;
    const float *Wgz, *bgz, *Wgr, *bgr, *Wgc, *bgc, *Wsh, *bsh, *Wl, *bl, *Wm, *bm;
    float *hidden, *nvs, *nvt, *Mcomb, *K1, *K2, *comb, *comb2, *z, *P1, *P2;
    float *q, *kk, *th1, *th2, *tar32;
};

void gru_step(hipStream_t stream, const Ptrs& p, const float* graph, long gstride)
{
    dim3 bg(8, NPART, B);   // 512 blocks x 8 waves
    hyper5_kernel<<<bg, 512, 0, stream>>>(p.P1, p.P2, p.hidden, p.K1, p.K2);
    gsgt5_kernel<<<B * N / 16, 256, 0, stream>>>(
        p.hidden, p.P1, p.P2, p.Wa1, p.ba1, p.Wa2, p.ba2, graph, gstride,
        p.Wsrc, p.bsrc, p.Wtgt, p.btgt, p.nvs, p.nvt);
    adp3_kernel<<<dim3(N / 4, B), 512, 0, stream>>>(
        p.nvs, p.nvt, p.A, p.hidden, graph, gstride, p.Mcomb, p.comb);
    bmm4_kernel<false><<<bg, 512, 0, stream>>>(p.P1, p.comb, p.comb, p.Mcomb);
    bmm4_kernel<true><<<bg, 512, 0, stream>>>(p.P2, p.comb, p.P1, p.Mcomb);
    zr5_kernel<<<B * N / 16, 256, 0, stream>>>(
        p.comb, p.P1, p.P2, p.Wgz, p.bgz, p.Wgr, p.bgr, p.hidden, p.z, p.comb2);
    bmm4_kernel<false><<<bg, 512, 0, stream>>>(p.P1, p.comb2, p.comb2, p.Mcomb);
    bmm4_kernel<true><<<bg, 512, 0, stream>>>(p.P2, p.comb2, p.P1, p.Mcomb);
    cup5_kernel<<<B * N / 16, 256, 0, stream>>>(
        p.comb2, p.P1, p.P2, p.Wgc, p.bgc, p.z, p.hidden);
}
}  // namespace

extern "C" void kernel_launch(void* const* d_in, const int* in_sizes, int n_in,
                              void* d_out, int out_size, void* d_ws, size_t ws_size,
                              hipStream_t stream)
{
    (void)in_sizes; (void)n_in; (void)out_size; (void)ws_size;
    Ptrs p;
    p.sample = (const float*)d_in[0];
    p.A      = (const float*)d_in[1];
    p.wq     = (const float*)d_in[2];
    p.wk     = (const float*)d_in[3];
    p.attn_bias  = (const float*)d_in[4];
    p.attn_trans = (const float*)d_in[5];
    p.Wt  = (const float*)d_in[6];
    p.bt_ = (const float*)d_in[7];
    p.Wa1 = (const float*)d_in[8];
    p.ba1 = (const float*)d_in[9];
    p.Wa2 = (const float*)d_in[10];
    p.ba2 = (const float*)d_in[11];
    p.Wsrc = (const float*)d_in[12];
    p.bsrc = (const float*)d_in[13];
    p.Wtgt = (const float*)d_in[14];
    p.btgt = (const float*)d_in[15];
    p.Wgz = (const float*)d_in[16];
    p.bgz = (const float*)d_in[17];
    p.Wgr = (const float*)d_in[18];
    p.bgr = (const float*)d_in[19];
    p.Wgc = (const float*)d_in[20];
    p.bgc = (const float*)d_in[21];
    p.Wsh = (const float*)d_in[22];
    p.bsh = (const float*)d_in[23];
    p.Wl  = (const float*)d_in[24];
    p.bl  = (const float*)d_in[25];
    p.Wm  = (const float*)d_in[26];
    p.bm  = (const float*)d_in[27];

    float* ws = (float*)d_ws;
    size_t off = 0;
    auto alloc = [&](size_t nelem) { float* r = ws + off; off += nelem; return r; };
    p.hidden = alloc((size_t)B * N * H);
    p.nvs    = alloc((size_t)B * N * E);
    p.nvt    = alloc((size_t)B * N * E);
    p.Mcomb  = alloc((size_t)B * N * N);
    p.K1     = alloc((size_t)N * N);
    p.K2     = alloc((size_t)N * N);
    p.comb   = alloc((size_t)B * N * CC);
    p.comb2  = alloc((size_t)B * N * CC);
    p.z      = alloc((size_t)B * N * H);
    p.P1     = alloc((size_t)NPART * B * N * CC);
    p.P2     = alloc((size_t)NPART * B * N * CC);
    p.q      = alloc((size_t)B * N * DA);
    p.kk     = alloc((size_t)B * 4 * N * DA);
    p.th1    = alloc((size_t)B * 4 * N * F);
    p.th2    = alloc((size_t)B * 4 * N * F);
    p.tar32  = alloc((size_t)B * N * TGN_OC);

    float* out = (float*)d_out;
    float* out_gat = out;
    float* out_gru = out + (size_t)B * N * F;
    float* out_fin = out + (size_t)2 * B * N * F;
    float* out_attn = out + (size_t)3 * B * N * F;

    hipMemsetAsync(p.hidden, 0, (size_t)B * N * H * sizeof(float), stream);
    scaleA_kernel<<<N * N / 256, 256, 0, stream>>>(p.A, p.K1);
    k2_kernel<<<dim3(32, 32), 256, 0, stream>>>(p.A, p.K2);

    for (int i = 0; i < 5; ++i) {
        const float* graph = p.sample + (size_t)(4 * i) * N * F;
        gru_step(stream, p, graph, (long)T * N * F);
    }

    qk_kernel<<<(B * N * DA + B * 4 * N * DA) / 256, 256, 0, stream>>>(
        p.sample, p.wq, p.wk, p.attn_bias, p.q, p.kk);
    scores3_kernel<<<dim3(32, 64), 256, 0, stream>>>(p.q, p.kk, p.attn_trans, out_attn);

    const float* srcbase = p.sample + (size_t)(T - 4) * N * F;
    tgn2_kernel<<<dim3(8, 64), 256, 0, stream>>>(
        p.A, out_attn, srcbase, (long)T * N * F, (long)N * F,
        srcbase, (long)T * N * F, (long)N * F, p.th1);
    tgn2_kernel<<<dim3(8, 64), 256, 0, stream>>>(
        p.A, out_attn, p.th1, (long)4 * N * F, (long)N * F,
        srcbase, (long)T * N * F, (long)N * F, p.th2);
    tgn_out_gat_kernel<<<B * N / 8, 256, 0, stream>>>(
        p.sample, p.th1, p.th2, p.Wt, p.bt_, p.Wsh, p.bsh, p.tar32, out_gat);

    gru_step(stream, p, out_gat, (long)N * F);

    final_kernel<<<(B * N * F) / 256, 256, 0, stream>>>(
        p.hidden, p.tar32, p.Wl, p.bl, p.Wm, p.bm, out_gru, out_fin);
}